// Round 4
// baseline (2396.001 us; speedup 1.0000x reference)
//
#include <hip/hip_runtime.h>
#include <math.h>

#define N_NODES 50000
#define N_EDGES 800000
#define R_REL 8
#define H_DIM 128
#define C_OUT 64

typedef __attribute__((ext_vector_type(8))) __bf16 bf16x8;
typedef __attribute__((ext_vector_type(4))) float f32x4;

// ---------------- CSR build (dst-sorted edge list) ----------------

__global__ void k_hist(const int* __restrict__ dst, int* __restrict__ hist) {
  int e = blockIdx.x * blockDim.x + threadIdx.x;
  if (e < N_EDGES) atomicAdd(&hist[dst[e]], 1);
}

__global__ void k_scan(const int* __restrict__ hist, int* __restrict__ rowptr,
                       int* __restrict__ cursor) {
  __shared__ int tmp[1024];
  int tid = threadIdx.x;
  int carry = 0;
  for (int base = 0; base < N_NODES; base += 1024) {
    int idx = base + tid;
    int v = (idx < N_NODES) ? hist[idx] : 0;
    tmp[tid] = v;
    __syncthreads();
    for (int off = 1; off < 1024; off <<= 1) {
      int t = (tid >= off) ? tmp[tid - off] : 0;
      __syncthreads();
      tmp[tid] += t;
      __syncthreads();
    }
    int excl = carry + tmp[tid] - v;
    if (idx < N_NODES) { rowptr[idx] = excl; cursor[idx] = excl; }
    carry += tmp[1023];
    __syncthreads();
  }
  if (tid == 0) rowptr[N_NODES] = carry;
}

__global__ void k_scatter(const int* __restrict__ src, const int* __restrict__ dst,
                          const int* __restrict__ et, int* __restrict__ cursor,
                          int* __restrict__ ssrc, int* __restrict__ setype) {
  int e = blockIdx.x * blockDim.x + threadIdx.x;
  if (e < N_EDGES) {
    int d = dst[e];
    int p = atomicAdd(&cursor[d], 1);
    ssrc[p] = src[e];
    setype[p] = et[e];
  }
}

// ---------------- W prep: split-bf16, pre-shuffled into MFMA A-fragment order ----------------
// Fragment chunk (ot,kb) holds 64 lanes x 8 bf16 contiguous (1KB):
//   lane(quad,c), j  ->  W[l][r][f=kb*32+quad*8+j][o=ot*16+c]
// Total per (l,r): 8ot * 4kb * 64lane * 8j = 16384 elements.

__global__ void k_prepwfrag(const float* __restrict__ W1, const float* __restrict__ W2,
                            const float* __restrict__ W3,
                            __bf16* __restrict__ Fhi, __bf16* __restrict__ Flo) {
  int t = blockIdx.x * 256 + threadIdx.x;   // 3*8*8*4*64 = 49152 threads
  if (t >= 49152) return;
  int lane = t & 63;
  int kb = (t >> 6) & 3;
  int ot = (t >> 8) & 7;
  int r  = (t >> 11) & 7;
  int l  = t >> 14;
  int c = lane & 15, quad = lane >> 4;
  const float* W = (l == 0) ? W1 : (l == 1) ? W2 : W3;
  const float* wp = W + ((size_t)r << 14) + (size_t)(kb * 32 + quad * 8) * 128 + ot * 16 + c;
  size_t ob = ((size_t)l * 8 + r) * 16384 + (size_t)((ot * 4 + kb) * 64 + lane) * 8;
#pragma unroll
  for (int j = 0; j < 8; ++j) {
    float v = wp[j * 128];
    __bf16 h = (__bf16)v;
    Fhi[ob + j] = h;
    Flo[ob + j] = (__bf16)(v - (float)h);
  }
}

// ---------------- wq/wk prep: wq[l][r][f] = sum_o W[l][r][f][o] * q[l][o] ----------------

__global__ void k_prepwq(const float* __restrict__ W1, const float* __restrict__ W2,
                         const float* __restrict__ W3,
                         const float* __restrict__ q1, const float* __restrict__ k1,
                         const float* __restrict__ q2, const float* __restrict__ k2,
                         const float* __restrict__ q3, const float* __restrict__ k3,
                         float* __restrict__ wq, float* __restrict__ wk) {
  int idx = blockIdx.x * blockDim.x + threadIdx.x;  // [l][r][f], 3*8*128
  if (idx >= 3 * R_REL * 128) return;
  int r = (idx >> 7) & 7;
  int f = idx & 127;
  int l = idx >> 10;
  const float* W  = (l == 0) ? W1 : (l == 1) ? W2 : W3;
  const float* qv = (l == 0) ? q1 : (l == 1) ? q2 : q3;
  const float* kv = (l == 0) ? k1 : (l == 1) ? k2 : k3;
  const float4* row = (const float4*)(W + ((size_t)r << 14) + ((size_t)f << 7));
  const float4* q4 = (const float4*)qv;
  const float4* k4 = (const float4*)kv;
  float sq = 0.f, sk = 0.f;
#pragma unroll 8
  for (int i = 0; i < 32; ++i) {
    float4 w = row[i], qq = q4[i], kk = k4[i];
    sq += w.x * qq.x + w.y * qq.y + w.z * qq.z + w.w * qq.w;
    sk += w.x * kk.x + w.y * kk.y + w.z * kk.z + w.w * kk.w;
  }
  wq[idx] = sq;
  wk[idx] = sk;
}

// ---------------- qx/kx: qx[n,r] = X[n,:] . wq[r,:] (pure fp32) ----------------

__global__ __launch_bounds__(256) void k_qkx(const float* __restrict__ X,
                                             const float* __restrict__ wq,
                                             const float* __restrict__ wk,
                                             float* __restrict__ qx, float* __restrict__ kx) {
  int t = blockIdx.x * 256 + threadIdx.x;
  int n = t >> 4;
  if (n >= N_NODES) return;
  int idx = t & 15;
  int r = idx >> 1;
  int isk = idx & 1;
  const float4* xv = (const float4*)(X + (size_t)n * 128);
  const float4* wv = (const float4*)((isk ? wk : wq) + r * 128);
  float s = 0.f;
#pragma unroll 8
  for (int i = 0; i < 32; ++i) {
    float4 a = xv[i], b = wv[i];
    s += a.x * b.x + a.y * b.y + a.z * b.z + a.w * b.w;
  }
  (isk ? kx : qx)[n * R_REL + r] = s;
}

// ---------------- MFMA transform: xr[n,r,:] = X[n,:] @ W[r] ----------------
// grid = (ceil(N/256), 8), block 512 (8 waves x 16 nodes x 2 iters).
// W[r] hi+lo staged once into 64KB LDS in fragment order; inner loop is
// ds_read_b128 + MFMA only. Split-bf16: hi*hi + lo*hi + hi*lo.

__global__ __launch_bounds__(512, 4) void k_transform_mfma(
    const float* __restrict__ X,
    const __bf16* __restrict__ Fhi, const __bf16* __restrict__ Flo,
    float* __restrict__ xr)
{
  __shared__ bf16x8 sW[4096];            // [0,2048) hi, [2048,4096) lo — 64 KB
  const int tid  = threadIdx.x;
  const int wave = tid >> 6;
  const int lane = tid & 63;
  const int quad = lane >> 4;
  const int c    = lane & 15;
  const int r    = blockIdx.y;

  // ---- stage W fragments (hi 32KB + lo 32KB) ----
  {
    const float4* gh = (const float4*)(Fhi + (size_t)r * 16384);
    const float4* gl = (const float4*)(Flo + (size_t)r * 16384);
    float4* s4 = (float4*)sW;
#pragma unroll
    for (int i = 0; i < 4; ++i) {
      s4[tid + i * 512] = gh[tid + i * 512];
      s4[2048 + tid + i * 512] = gl[tid + i * 512];
    }
  }
  __syncthreads();

#pragma unroll 1
  for (int it = 0; it < 2; ++it) {
    const int node = blockIdx.x * 256 + it * 128 + wave * 16 + c;
    const int nclamp = (node < N_NODES) ? node : (N_NODES - 1);
    const float4* Xv = (const float4*)(X + (size_t)nclamp * 128);

    // B fragments: X row in split bf16
    bf16x8 Bhi[4], Blo[4];
#pragma unroll
    for (int kb = 0; kb < 4; ++kb) {
      float4 a = Xv[kb * 8 + quad * 2];
      float4 b = Xv[kb * 8 + quad * 2 + 1];
      float xf[8] = {a.x, a.y, a.z, a.w, b.x, b.y, b.z, b.w};
#pragma unroll
      for (int j = 0; j < 8; ++j) {
        __bf16 h = (__bf16)xf[j];
        Bhi[kb][j] = h;
        Blo[kb][j] = (__bf16)(xf[j] - (float)h);
      }
    }

    f32x4 acc[8];
#pragma unroll
    for (int ot = 0; ot < 8; ++ot) acc[ot] = (f32x4){0.f, 0.f, 0.f, 0.f};

#pragma unroll
    for (int kb = 0; kb < 4; ++kb) {
#pragma unroll
      for (int ot = 0; ot < 8; ++ot) {
        bf16x8 whi = sW[(ot * 4 + kb) * 64 + lane];
        bf16x8 wlo = sW[2048 + (ot * 4 + kb) * 64 + lane];
        acc[ot] = __builtin_amdgcn_mfma_f32_16x16x32_bf16(whi, Bhi[kb], acc[ot], 0, 0, 0);
        acc[ot] = __builtin_amdgcn_mfma_f32_16x16x32_bf16(wlo, Bhi[kb], acc[ot], 0, 0, 0);
        acc[ot] = __builtin_amdgcn_mfma_f32_16x16x32_bf16(whi, Blo[kb], acc[ot], 0, 0, 0);
      }
    }

    // D: col=node(c), row = ot*16 + quad*4 + reg -> float4 store per ot
    if (node < N_NODES) {
      float* dp = xr + (((size_t)node * R_REL + r) << 7) + quad * 4;
#pragma unroll
      for (int ot = 0; ot < 8; ++ot) {
        *(float4*)(dp + ot * 16) = make_float4(acc[ot][0], acc[ot][1], acc[ot][2], acc[ot][3]);
      }
    }
  }
}

// ---------------- per-dst-node online-softmax aggregation ----------------

__global__ __launch_bounds__(64) void k_agg(
    const float* __restrict__ xr, const float* __restrict__ qx, const float* __restrict__ kx,
    const int* __restrict__ rowptr, const int* __restrict__ ssrc, const int* __restrict__ setype,
    const float* __restrict__ bias, float* __restrict__ out)
{
  const int nd = blockIdx.x;
  const int lane = threadIdx.x;
  const int s = rowptr[nd];
  const int deg = rowptr[nd + 1] - s;

  float m = -INFINITY, sum = 0.f, ax = 0.f, ay = 0.f;
  const float2* xr2 = (const float2*)xr;

  for (int c = 0; c < deg; c += 64) {
    int idx = c + lane;
    bool valid = idx < deg;
    int sn = 0, et = 0;
    float a = -INFINITY;
    if (valid) {
      sn = ssrc[s + idx];
      et = setype[s + idx];
      a = qx[nd * R_REL + et] + kx[sn * R_REL + et];
      a = (a >= 0.f) ? a : 0.2f * a;   // leaky relu, slope 0.2
    }
    float cm = a;
#pragma unroll
    for (int off = 32; off > 0; off >>= 1) cm = fmaxf(cm, __shfl_xor(cm, off));
    float mnew = fmaxf(m, cm);
    float scale = (m == -INFINITY) ? 0.f : __expf(m - mnew);
    sum *= scale; ax *= scale; ay *= scale;
    m = mnew;
    float e = valid ? __expf(a - m) : 0.f;
    float cs = e;
#pragma unroll
    for (int off = 32; off > 0; off >>= 1) cs += __shfl_xor(cs, off);
    sum += cs;
    int cnt = (deg - c < 64) ? (deg - c) : 64;
    for (int j = 0; j < cnt; ++j) {
      float w = __shfl(e, j);
      int sj = __shfl(sn, j);
      int ej = __shfl(et, j);
      float2 v = xr2[((size_t)sj * R_REL + ej) * 64 + lane];
      ax += w * v.x;
      ay += w * v.y;
    }
  }
  float inv = (deg > 0) ? 1.f / sum : 0.f;
  float2 bb = ((const float2*)bias)[lane];
  float ox = fmaxf(ax * inv + bb.x, 0.f);
  float oy = fmaxf(ay * inv + bb.y, 0.f);
  ((float2*)out)[(size_t)nd * 64 + lane] = make_float2(ox, oy);
}

// ---------------- final linear + log_softmax ----------------

__global__ __launch_bounds__(64) void k_final(
    const float* __restrict__ h, const float* __restrict__ lw, const float* __restrict__ lb,
    float* __restrict__ out)
{
  const int nd = blockIdx.x;
  const int c = threadIdx.x;
  const float* hrow = h + (size_t)nd * 128;
  float acc = lb[c];
#pragma unroll 8
  for (int f = 0; f < 128; ++f) acc += hrow[f] * lw[f * 64 + c];
  float mx = acc;
#pragma unroll
  for (int off = 32; off > 0; off >>= 1) mx = fmaxf(mx, __shfl_xor(mx, off));
  float e = __expf(acc - mx);
  float ssum = e;
#pragma unroll
  for (int off = 32; off > 0; off >>= 1) ssum += __shfl_xor(ssum, off);
  out[(size_t)nd * 64 + c] = acc - mx - __logf(ssum);
}

// ---------------- launch ----------------

extern "C" void kernel_launch(void* const* d_in, const int* in_sizes, int n_in,
                              void* d_out, int out_size, void* d_ws, size_t ws_size,
                              hipStream_t stream) {
  const float* x   = (const float*)d_in[0];
  const int* ei    = (const int*)d_in[1];
  const int* etype = (const int*)d_in[2];
  const float* W1 = (const float*)d_in[3];
  const float* q1 = (const float*)d_in[4];
  const float* k1 = (const float*)d_in[5];
  const float* b1 = (const float*)d_in[6];
  const float* W2 = (const float*)d_in[7];
  const float* q2 = (const float*)d_in[8];
  const float* k2 = (const float*)d_in[9];
  const float* b2 = (const float*)d_in[10];
  const float* W3 = (const float*)d_in[11];
  const float* q3 = (const float*)d_in[12];
  const float* k3 = (const float*)d_in[13];
  const float* b3 = (const float*)d_in[14];
  const float* lw = (const float*)d_in[15];
  const float* lb = (const float*)d_in[16];
  float* outp = (float*)d_out;

  char* p = (char*)d_ws;
  auto alloc = [&](size_t bytes) {
    char* r = p;
    p += (bytes + 255) & ~(size_t)255;
    return r;
  };
  float* xr   = (float*)alloc((size_t)N_NODES * R_REL * H_DIM * 4);  // 204.8 MB
  float* qx   = (float*)alloc((size_t)N_NODES * R_REL * 4);
  float* kx   = (float*)alloc((size_t)N_NODES * R_REL * 4);
  float* hA   = (float*)alloc((size_t)N_NODES * H_DIM * 4);
  float* hB   = (float*)alloc((size_t)N_NODES * H_DIM * 4);
  int* rowptr = (int*)alloc((size_t)(N_NODES + 1) * 4);
  int* cursor = (int*)alloc((size_t)N_NODES * 4);
  int* hist   = (int*)alloc((size_t)N_NODES * 4);
  int* ssrc   = (int*)alloc((size_t)N_EDGES * 4);
  int* setype = (int*)alloc((size_t)N_EDGES * 4);
  __bf16* Fhi = (__bf16*)alloc((size_t)3 * R_REL * 128 * 128 * 2);   // 786 KB
  __bf16* Flo = (__bf16*)alloc((size_t)3 * R_REL * 128 * 128 * 2);
  float* wq   = (float*)alloc((size_t)3 * R_REL * 128 * 4);
  float* wk   = (float*)alloc((size_t)3 * R_REL * 128 * 4);

  const int* src = ei;            // edge_index[0]
  const int* dst = ei + N_EDGES;  // edge_index[1]

  // CSR build + W prep
  hipMemsetAsync(hist, 0, (size_t)N_NODES * 4, stream);
  k_hist<<<(N_EDGES + 255) / 256, 256, 0, stream>>>(dst, hist);
  k_prepwfrag<<<192, 256, 0, stream>>>(W1, W2, W3, Fhi, Flo);
  k_prepwq<<<(3 * R_REL * 128 + 255) / 256, 256, 0, stream>>>(W1, W2, W3, q1, k1, q2, k2, q3, k3, wq, wk);
  k_scan<<<1, 1024, 0, stream>>>(hist, rowptr, cursor);
  k_scatter<<<(N_EDGES + 255) / 256, 256, 0, stream>>>(src, dst, etype, cursor, ssrc, setype);

  dim3 tgrid((N_NODES + 255) / 256, R_REL);
  const int qgrid = (N_NODES * 16 + 255) / 256;
  const size_t WFL = (size_t)R_REL * 128 * 128;  // per-layer fragment stride
  const size_t WQL = (size_t)R_REL * 128;

  // layer 1
  k_transform_mfma<<<tgrid, 512, 0, stream>>>(x, Fhi, Flo, xr);
  k_qkx<<<qgrid, 256, 0, stream>>>(x, wq, wk, qx, kx);
  k_agg<<<N_NODES, 64, 0, stream>>>(xr, qx, kx, rowptr, ssrc, setype, b1, hA);
  // layer 2
  k_transform_mfma<<<tgrid, 512, 0, stream>>>(hA, Fhi + WFL, Flo + WFL, xr);
  k_qkx<<<qgrid, 256, 0, stream>>>(hA, wq + WQL, wk + WQL, qx, kx);
  k_agg<<<N_NODES, 64, 0, stream>>>(xr, qx, kx, rowptr, ssrc, setype, b2, hB);
  // layer 3
  k_transform_mfma<<<tgrid, 512, 0, stream>>>(hB, Fhi + 2 * WFL, Flo + 2 * WFL, xr);
  k_qkx<<<qgrid, 256, 0, stream>>>(hB, wq + 2 * WQL, wk + 2 * WQL, qx, kx);
  k_agg<<<N_NODES, 64, 0, stream>>>(xr, qx, kx, rowptr, ssrc, setype, b3, hA);
  // final linear + log_softmax
  k_final<<<N_NODES, 64, 0, stream>>>(hA, lw, lb, outp);
}

// Round 5
// 1008.092 us; speedup vs baseline: 2.3768x; 2.3768x over previous
//
#include <hip/hip_runtime.h>
#include <math.h>

#define N_NODES 50000
#define N_EDGES 800000
#define R_REL 8
#define H_DIM 128
#define C_OUT 64

typedef __attribute__((ext_vector_type(8))) __bf16 bf16x8;
typedef __attribute__((ext_vector_type(4))) float f32x4;

// ---------------- CSR build (dst-sorted edge list) ----------------

__global__ void k_hist(const int* __restrict__ dst, int* __restrict__ hist) {
  int e = blockIdx.x * blockDim.x + threadIdx.x;
  if (e < N_EDGES) atomicAdd(&hist[dst[e]], 1);
}

__global__ void k_scan(const int* __restrict__ hist, int* __restrict__ rowptr,
                       int* __restrict__ cursor) {
  __shared__ int tmp[1024];
  int tid = threadIdx.x;
  int carry = 0;
  for (int base = 0; base < N_NODES; base += 1024) {
    int idx = base + tid;
    int v = (idx < N_NODES) ? hist[idx] : 0;
    tmp[tid] = v;
    __syncthreads();
    for (int off = 1; off < 1024; off <<= 1) {
      int t = (tid >= off) ? tmp[tid - off] : 0;
      __syncthreads();
      tmp[tid] += t;
      __syncthreads();
    }
    int excl = carry + tmp[tid] - v;
    if (idx < N_NODES) { rowptr[idx] = excl; cursor[idx] = excl; }
    carry += tmp[1023];
    __syncthreads();
  }
  if (tid == 0) rowptr[N_NODES] = carry;
}

__global__ void k_scatter(const int* __restrict__ src, const int* __restrict__ dst,
                          const int* __restrict__ et, int* __restrict__ cursor,
                          int* __restrict__ ssrc, int* __restrict__ setype) {
  int e = blockIdx.x * blockDim.x + threadIdx.x;
  if (e < N_EDGES) {
    int d = dst[e];
    int p = atomicAdd(&cursor[d], 1);
    ssrc[p] = src[e];
    setype[p] = et[e];
  }
}

// ---------------- W prep: concat-K (k = r*128+f), split-bf16, MFMA A-fragment order ----
// Layout per layer: [kc(32)][ot(8)][lane(64)][j(8)]  (k = kc*32 + quad*8 + j, o = ot*16 + c)
// A-frag semantics: A[m = o][k], lane=(quad,c), 8 bf16 per lane per (kc,ot).

__global__ void k_prepwfrag(const float* __restrict__ W1, const float* __restrict__ W2,
                            const float* __restrict__ W3,
                            __bf16* __restrict__ Fhi, __bf16* __restrict__ Flo) {
  int t = blockIdx.x * 256 + threadIdx.x;   // 3*32*8*64 = 49152
  if (t >= 49152) return;
  int lane = t & 63;
  int ot = (t >> 6) & 7;
  int kc = (t >> 9) & 31;
  int l  = t >> 14;
  int c = lane & 15, quad = lane >> 4;
  const float* W = (l == 0) ? W1 : (l == 1) ? W2 : W3;
  int k0 = kc * 32 + quad * 8;          // 8-aligned, never crosses a 128 boundary
  int r = k0 >> 7;
  int f0 = k0 & 127;
  int o = ot * 16 + c;
  const float* wp = W + ((size_t)r << 14) + (size_t)f0 * 128 + o;
  size_t ob = ((size_t)l * 131072) + (((size_t)kc * 8 + ot) * 64 + lane) * 8;
#pragma unroll
  for (int j = 0; j < 8; ++j) {
    float v = wp[j * 128];
    __bf16 h = (__bf16)v;
    Fhi[ob + j] = h;
    Flo[ob + j] = (__bf16)(v - (float)h);
  }
}

// ---------------- wq/wk prep: wq[l][r][f] = sum_o W[l][r][f][o] * q[l][o] ----------------

__global__ void k_prepwq(const float* __restrict__ W1, const float* __restrict__ W2,
                         const float* __restrict__ W3,
                         const float* __restrict__ q1, const float* __restrict__ k1,
                         const float* __restrict__ q2, const float* __restrict__ k2,
                         const float* __restrict__ q3, const float* __restrict__ k3,
                         float* __restrict__ wq, float* __restrict__ wk) {
  int idx = blockIdx.x * blockDim.x + threadIdx.x;  // [l][r][f], 3*8*128
  if (idx >= 3 * R_REL * 128) return;
  int r = (idx >> 7) & 7;
  int f = idx & 127;
  int l = idx >> 10;
  const float* W  = (l == 0) ? W1 : (l == 1) ? W2 : W3;
  const float* qv = (l == 0) ? q1 : (l == 1) ? q2 : q3;
  const float* kv = (l == 0) ? k1 : (l == 1) ? k2 : k3;
  const float4* row = (const float4*)(W + ((size_t)r << 14) + ((size_t)f << 7));
  const float4* q4 = (const float4*)qv;
  const float4* k4 = (const float4*)kv;
  float sq = 0.f, sk = 0.f;
#pragma unroll 8
  for (int i = 0; i < 32; ++i) {
    float4 w = row[i], qq = q4[i], kk = k4[i];
    sq += w.x * qq.x + w.y * qq.y + w.z * qq.z + w.w * qq.w;
    sk += w.x * kk.x + w.y * kk.y + w.z * kk.z + w.w * kk.w;
  }
  wq[idx] = sq;
  wk[idx] = sk;
}

// ---------------- qx/kx: qx[n,r] = X[n,:] . wq[r,:] (pure fp32) ----------------

__global__ __launch_bounds__(256) void k_qkx(const float* __restrict__ X,
                                             const float* __restrict__ wq,
                                             const float* __restrict__ wk,
                                             float* __restrict__ qx, float* __restrict__ kx) {
  int t = blockIdx.x * 256 + threadIdx.x;
  int n = t >> 4;
  if (n >= N_NODES) return;
  int idx = t & 15;
  int r = idx >> 1;
  int isk = idx & 1;
  const float4* xv = (const float4*)(X + (size_t)n * 128);
  const float4* wv = (const float4*)((isk ? wk : wq) + r * 128);
  float s = 0.f;
#pragma unroll 8
  for (int i = 0; i < 32; ++i) {
    float4 a = xv[i], b = wv[i];
    s += a.x * b.x + a.y * b.y + a.z * b.z + a.w * b.w;
  }
  (isk ? kx : qx)[n * R_REL + r] = s;
}

// ---------------- phase A: per-dst online-softmax, accumulate INPUT features per relation ----
// agg[d][r][f] = sum_{e: dst=d, et=r} softmaxw_e * x[src_e][f].  One wave per node,
// lane holds float2 (feats 2l,2l+1) for each of 8 relations = 16 VGPR acc.

__global__ __launch_bounds__(64) void k_agg_feat(
    const float* __restrict__ x, const float* __restrict__ qx, const float* __restrict__ kx,
    const int* __restrict__ rowptr, const int* __restrict__ ssrc, const int* __restrict__ setype,
    float* __restrict__ agg)
{
  const int nd = blockIdx.x;
  const int lane = threadIdx.x;
  const int s = rowptr[nd];
  const int deg = rowptr[nd + 1] - s;

  float m = -INFINITY, sum = 0.f;
  float2 acc[R_REL];
#pragma unroll
  for (int r = 0; r < R_REL; ++r) acc[r] = make_float2(0.f, 0.f);
  const float2* x2 = (const float2*)x;

  for (int c = 0; c < deg; c += 64) {
    int idx = c + lane;
    bool valid = idx < deg;
    int sn = 0, et = 0;
    float a = -INFINITY;
    if (valid) {
      sn = ssrc[s + idx];
      et = setype[s + idx];
      a = qx[nd * R_REL + et] + kx[sn * R_REL + et];
      a = (a >= 0.f) ? a : 0.2f * a;   // leaky relu, slope 0.2
    }
    float cm = a;
#pragma unroll
    for (int off = 32; off > 0; off >>= 1) cm = fmaxf(cm, __shfl_xor(cm, off));
    float mnew = fmaxf(m, cm);
    float scale = (m == -INFINITY) ? 0.f : __expf(m - mnew);
    sum *= scale;
#pragma unroll
    for (int r = 0; r < R_REL; ++r) { acc[r].x *= scale; acc[r].y *= scale; }
    m = mnew;
    float e = valid ? __expf(a - m) : 0.f;
    float cs = e;
#pragma unroll
    for (int off = 32; off > 0; off >>= 1) cs += __shfl_xor(cs, off);
    sum += cs;
    int cnt = (deg - c < 64) ? (deg - c) : 64;
    for (int j = 0; j < cnt; ++j) {
      float w = __shfl(e, j);
      int sj = __shfl(sn, j);
      int ej = __shfl(et, j);           // wave-uniform
      float2 v = x2[(size_t)sj * 64 + lane];
      switch (ej) {
        case 0: acc[0].x += w * v.x; acc[0].y += w * v.y; break;
        case 1: acc[1].x += w * v.x; acc[1].y += w * v.y; break;
        case 2: acc[2].x += w * v.x; acc[2].y += w * v.y; break;
        case 3: acc[3].x += w * v.x; acc[3].y += w * v.y; break;
        case 4: acc[4].x += w * v.x; acc[4].y += w * v.y; break;
        case 5: acc[5].x += w * v.x; acc[5].y += w * v.y; break;
        case 6: acc[6].x += w * v.x; acc[6].y += w * v.y; break;
        default: acc[7].x += w * v.x; acc[7].y += w * v.y; break;
      }
    }
  }
  float inv = (deg > 0) ? 1.f / sum : 0.f;
  float2* ag2 = (float2*)agg;
#pragma unroll
  for (int r = 0; r < R_REL; ++r) {
    ag2[((size_t)nd * R_REL + r) * 64 + lane] = make_float2(acc[r].x * inv, acc[r].y * inv);
  }
}

// ---------------- phase B: h[n,:] = relu( sum_k agg[n][k] * Wcat[k][:] + b ) ----------------
// M=128 outputs, K=1024 (r,f concat), N=node. block 512 = 8 waves x 16 nodes = 128 nodes.
// W (split-bf16, fragment order) staged per 128-K super-chunk into 64KB LDS.

__global__ __launch_bounds__(512, 4) void k_gemm_out(
    const float* __restrict__ agg,
    const __bf16* __restrict__ Fhi, const __bf16* __restrict__ Flo,
    const float* __restrict__ bias, float* __restrict__ out)
{
  __shared__ bf16x8 sW[4096];            // [0,2048) hi, [2048,4096) lo — 64 KB
  const int tid  = threadIdx.x;
  const int wave = tid >> 6;
  const int lane = tid & 63;
  const int quad = lane >> 4;
  const int c    = lane & 15;

  const int node = blockIdx.x * 128 + wave * 16 + c;
  const int nclamp = (node < N_NODES) ? node : (N_NODES - 1);
  const float4* Av = (const float4*)(agg + (size_t)nclamp * 1024);

  f32x4 acc[8];
#pragma unroll
  for (int ot = 0; ot < 8; ++ot) acc[ot] = (f32x4){0.f, 0.f, 0.f, 0.f};

#pragma unroll 1
  for (int s = 0; s < 8; ++s) {          // K super-chunks of 128
    __syncthreads();
    {
      const float4* gh = (const float4*)(Fhi + (size_t)s * 16384);
      const float4* gl = (const float4*)(Flo + (size_t)s * 16384);
      float4* s4 = (float4*)sW;
#pragma unroll
      for (int i = 0; i < 4; ++i) {
        s4[tid + i * 512] = gh[tid + i * 512];
        s4[2048 + tid + i * 512] = gl[tid + i * 512];
      }
    }
    // B fragments for this super-chunk: agg[node][s*128 + kb*32 + quad*8 + j]
    bf16x8 Bh[4], Bl[4];
#pragma unroll
    for (int kb = 0; kb < 4; ++kb) {
      float4 a = Av[s * 32 + kb * 8 + quad * 2];
      float4 b = Av[s * 32 + kb * 8 + quad * 2 + 1];
      float xf[8] = {a.x, a.y, a.z, a.w, b.x, b.y, b.z, b.w};
#pragma unroll
      for (int j = 0; j < 8; ++j) {
        __bf16 h = (__bf16)xf[j];
        Bh[kb][j] = h;
        Bl[kb][j] = (__bf16)(xf[j] - (float)h);
      }
    }
    __syncthreads();
#pragma unroll
    for (int kb = 0; kb < 4; ++kb) {
#pragma unroll
      for (int ot = 0; ot < 8; ++ot) {
        bf16x8 whi = sW[(kb * 8 + ot) * 64 + lane];
        bf16x8 wlo = sW[2048 + (kb * 8 + ot) * 64 + lane];
        acc[ot] = __builtin_amdgcn_mfma_f32_16x16x32_bf16(whi, Bh[kb], acc[ot], 0, 0, 0);
        acc[ot] = __builtin_amdgcn_mfma_f32_16x16x32_bf16(wlo, Bh[kb], acc[ot], 0, 0, 0);
        acc[ot] = __builtin_amdgcn_mfma_f32_16x16x32_bf16(whi, Bl[kb], acc[ot], 0, 0, 0);
      }
    }
  }

  // D: col=node(c), row = o = ot*16 + quad*4 + reg.  Fuse bias + relu.
  if (node < N_NODES) {
    float* dp = out + ((size_t)node << 7) + quad * 4;
#pragma unroll
    for (int ot = 0; ot < 8; ++ot) {
      float4 bb = *(const float4*)(bias + ot * 16 + quad * 4);
      *(float4*)(dp + ot * 16) = make_float4(
          fmaxf(acc[ot][0] + bb.x, 0.f), fmaxf(acc[ot][1] + bb.y, 0.f),
          fmaxf(acc[ot][2] + bb.z, 0.f), fmaxf(acc[ot][3] + bb.w, 0.f));
    }
  }
}

// ---------------- final linear + log_softmax ----------------

__global__ __launch_bounds__(64) void k_final(
    const float* __restrict__ h, const float* __restrict__ lw, const float* __restrict__ lb,
    float* __restrict__ out)
{
  const int nd = blockIdx.x;
  const int c = threadIdx.x;
  const float* hrow = h + (size_t)nd * 128;
  float acc = lb[c];
#pragma unroll 8
  for (int f = 0; f < 128; ++f) acc += hrow[f] * lw[f * 64 + c];
  float mx = acc;
#pragma unroll
  for (int off = 32; off > 0; off >>= 1) mx = fmaxf(mx, __shfl_xor(mx, off));
  float e = __expf(acc - mx);
  float ssum = e;
#pragma unroll
  for (int off = 32; off > 0; off >>= 1) ssum += __shfl_xor(ssum, off);
  out[(size_t)nd * 64 + c] = acc - mx - __logf(ssum);
}

// ---------------- launch ----------------

extern "C" void kernel_launch(void* const* d_in, const int* in_sizes, int n_in,
                              void* d_out, int out_size, void* d_ws, size_t ws_size,
                              hipStream_t stream) {
  const float* x   = (const float*)d_in[0];
  const int* ei    = (const int*)d_in[1];
  const int* etype = (const int*)d_in[2];
  const float* W1 = (const float*)d_in[3];
  const float* q1 = (const float*)d_in[4];
  const float* k1 = (const float*)d_in[5];
  const float* b1 = (const float*)d_in[6];
  const float* W2 = (const float*)d_in[7];
  const float* q2 = (const float*)d_in[8];
  const float* k2 = (const float*)d_in[9];
  const float* b2 = (const float*)d_in[10];
  const float* W3 = (const float*)d_in[11];
  const float* q3 = (const float*)d_in[12];
  const float* k3 = (const float*)d_in[13];
  const float* b3 = (const float*)d_in[14];
  const float* lw = (const float*)d_in[15];
  const float* lb = (const float*)d_in[16];
  float* outp = (float*)d_out;

  char* p = (char*)d_ws;
  auto alloc = [&](size_t bytes) {
    char* r = p;
    p += (bytes + 255) & ~(size_t)255;
    return r;
  };
  float* agg  = (float*)alloc((size_t)N_NODES * R_REL * H_DIM * 4);  // 204.8 MB
  float* qx   = (float*)alloc((size_t)N_NODES * R_REL * 4);
  float* kx   = (float*)alloc((size_t)N_NODES * R_REL * 4);
  float* hA   = (float*)alloc((size_t)N_NODES * H_DIM * 4);
  float* hB   = (float*)alloc((size_t)N_NODES * H_DIM * 4);
  int* rowptr = (int*)alloc((size_t)(N_NODES + 1) * 4);
  int* cursor = (int*)alloc((size_t)N_NODES * 4);
  int* hist   = (int*)alloc((size_t)N_NODES * 4);
  int* ssrc   = (int*)alloc((size_t)N_EDGES * 4);
  int* setype = (int*)alloc((size_t)N_EDGES * 4);
  __bf16* Fhi = (__bf16*)alloc((size_t)3 * 131072 * 2);   // 786 KB
  __bf16* Flo = (__bf16*)alloc((size_t)3 * 131072 * 2);
  float* wq   = (float*)alloc((size_t)3 * R_REL * 128 * 4);
  float* wk   = (float*)alloc((size_t)3 * R_REL * 128 * 4);

  const int* src = ei;            // edge_index[0]
  const int* dst = ei + N_EDGES;  // edge_index[1]

  // CSR build + W prep
  hipMemsetAsync(hist, 0, (size_t)N_NODES * 4, stream);
  k_hist<<<(N_EDGES + 255) / 256, 256, 0, stream>>>(dst, hist);
  k_prepwfrag<<<192, 256, 0, stream>>>(W1, W2, W3, Fhi, Flo);
  k_prepwq<<<(3 * R_REL * 128 + 255) / 256, 256, 0, stream>>>(W1, W2, W3, q1, k1, q2, k2, q3, k3, wq, wk);
  k_scan<<<1, 1024, 0, stream>>>(hist, rowptr, cursor);
  k_scatter<<<(N_EDGES + 255) / 256, 256, 0, stream>>>(src, dst, etype, cursor, ssrc, setype);

  const int qgrid = (N_NODES * 16 + 255) / 256;
  const int ggrid = (N_NODES + 127) / 128;
  const size_t WFL = 131072;                     // per-layer fragment stride (bf16 elems)
  const size_t WQL = (size_t)R_REL * 128;

  // layer 1
  k_qkx<<<qgrid, 256, 0, stream>>>(x, wq, wk, qx, kx);
  k_agg_feat<<<N_NODES, 64, 0, stream>>>(x, qx, kx, rowptr, ssrc, setype, agg);
  k_gemm_out<<<ggrid, 512, 0, stream>>>(agg, Fhi, Flo, b1, hA);
  // layer 2
  k_qkx<<<qgrid, 256, 0, stream>>>(hA, wq + WQL, wk + WQL, qx, kx);
  k_agg_feat<<<N_NODES, 64, 0, stream>>>(hA, qx, kx, rowptr, ssrc, setype, agg);
  k_gemm_out<<<ggrid, 512, 0, stream>>>(agg, Fhi + WFL, Flo + WFL, b2, hB);
  // layer 3
  k_qkx<<<qgrid, 256, 0, stream>>>(hB, wq + 2 * WQL, wk + 2 * WQL, qx, kx);
  k_agg_feat<<<N_NODES, 64, 0, stream>>>(hB, qx, kx, rowptr, ssrc, setype, agg);
  k_gemm_out<<<ggrid, 512, 0, stream>>>(agg, Fhi + 2 * WFL, Flo + 2 * WFL, b3, hA);
  // final linear + log_softmax
  k_final<<<N_NODES, 64, 0, stream>>>(hA, lw, lb, outp);
}

// Round 6
// 800.515 us; speedup vs baseline: 2.9931x; 1.2593x over previous
//
#include <hip/hip_runtime.h>
#include <math.h>

#define N_NODES 50000
#define N_EDGES 800000
#define R_REL 8
#define H_DIM 128
#define C_OUT 64

typedef __attribute__((ext_vector_type(8))) __bf16 bf16x8;
typedef __attribute__((ext_vector_type(2))) __bf16 bf16x2;
typedef __attribute__((ext_vector_type(4))) float f32x4;

// ---------------- CSR build (dst-sorted edge list) ----------------

__global__ void k_hist(const int* __restrict__ dst, int* __restrict__ hist) {
  int e = blockIdx.x * blockDim.x + threadIdx.x;
  if (e < N_EDGES) atomicAdd(&hist[dst[e]], 1);
}

// multi-block exclusive scan: scan1 (per-1024-block) -> scan2 (block sums) -> scan3 (add offsets)
__global__ __launch_bounds__(1024) void k_scan1(const int* __restrict__ hist,
                                                int* __restrict__ excl, int* __restrict__ bsum) {
  __shared__ int tmp[1024];
  int b = blockIdx.x, tid = threadIdx.x;
  int idx = b * 1024 + tid;
  int v = (idx < N_NODES) ? hist[idx] : 0;
  tmp[tid] = v;
  __syncthreads();
  for (int off = 1; off < 1024; off <<= 1) {
    int t = (tid >= off) ? tmp[tid - off] : 0;
    __syncthreads();
    tmp[tid] += t;
    __syncthreads();
  }
  if (idx < N_NODES) excl[idx] = tmp[tid] - v;
  if (tid == 1023) bsum[b] = tmp[1023];
}

__global__ void k_scan2(const int* __restrict__ bsum, int* __restrict__ boff) {
  if (threadIdx.x == 0) {
    int nb = (N_NODES + 1023) / 1024;
    int s = 0;
    for (int i = 0; i < nb; ++i) { boff[i] = s; s += bsum[i]; }
  }
}

__global__ void k_scan3(const int* __restrict__ excl, const int* __restrict__ boff,
                        int* __restrict__ rowptr, int* __restrict__ cursor) {
  int idx = blockIdx.x * blockDim.x + threadIdx.x;
  if (idx < N_NODES) {
    int v = excl[idx] + boff[idx >> 10];
    rowptr[idx] = v;
    cursor[idx] = v;
  }
  if (idx == 0) rowptr[N_NODES] = N_EDGES;
}

__global__ void k_scatter(const int* __restrict__ src, const int* __restrict__ dst,
                          const int* __restrict__ et, int* __restrict__ cursor,
                          int* __restrict__ ssrc, int* __restrict__ setype) {
  int e = blockIdx.x * blockDim.x + threadIdx.x;
  if (e < N_EDGES) {
    int d = dst[e];
    int p = atomicAdd(&cursor[d], 1);
    ssrc[p] = src[e];
    setype[p] = et[e];
  }
}

// ---------------- W prep: concat-K (k = r*128+f), split-bf16, MFMA A-fragment order ----
// Layout per layer: [kc(32)][ot(8)][lane(64)][j(8)]  (k = kc*32 + quad*8 + j, o = ot*16 + c)

__global__ void k_prepwfrag(const float* __restrict__ W1, const float* __restrict__ W2,
                            const float* __restrict__ W3,
                            __bf16* __restrict__ Fhi, __bf16* __restrict__ Flo) {
  int t = blockIdx.x * 256 + threadIdx.x;   // 3*32*8*64 = 49152
  if (t >= 49152) return;
  int lane = t & 63;
  int ot = (t >> 6) & 7;
  int kc = (t >> 9) & 31;
  int l  = t >> 14;
  int c = lane & 15, quad = lane >> 4;
  const float* W = (l == 0) ? W1 : (l == 1) ? W2 : W3;
  int k0 = kc * 32 + quad * 8;          // 8-aligned, never crosses a 128 boundary
  int r = k0 >> 7;
  int f0 = k0 & 127;
  int o = ot * 16 + c;
  const float* wp = W + ((size_t)r << 14) + (size_t)f0 * 128 + o;
  size_t ob = ((size_t)l * 131072) + (((size_t)kc * 8 + ot) * 64 + lane) * 8;
#pragma unroll
  for (int j = 0; j < 8; ++j) {
    float v = wp[j * 128];
    __bf16 h = (__bf16)v;
    Fhi[ob + j] = h;
    Flo[ob + j] = (__bf16)(v - (float)h);
  }
}

// ---------------- wq/wk prep: wq[l][r][f] = sum_o W[l][r][f][o] * q[l][o] ----------------

__global__ void k_prepwq(const float* __restrict__ W1, const float* __restrict__ W2,
                         const float* __restrict__ W3,
                         const float* __restrict__ q1, const float* __restrict__ k1,
                         const float* __restrict__ q2, const float* __restrict__ k2,
                         const float* __restrict__ q3, const float* __restrict__ k3,
                         float* __restrict__ wq, float* __restrict__ wk) {
  int idx = blockIdx.x * blockDim.x + threadIdx.x;  // [l][r][f], 3*8*128
  if (idx >= 3 * R_REL * 128) return;
  int r = (idx >> 7) & 7;
  int f = idx & 127;
  int l = idx >> 10;
  const float* W  = (l == 0) ? W1 : (l == 1) ? W2 : W3;
  const float* qv = (l == 0) ? q1 : (l == 1) ? q2 : q3;
  const float* kv = (l == 0) ? k1 : (l == 1) ? k2 : k3;
  const float4* row = (const float4*)(W + ((size_t)r << 14) + ((size_t)f << 7));
  const float4* q4 = (const float4*)qv;
  const float4* k4 = (const float4*)kv;
  float sq = 0.f, sk = 0.f;
#pragma unroll 8
  for (int i = 0; i < 32; ++i) {
    float4 w = row[i], qq = q4[i], kk = k4[i];
    sq += w.x * qq.x + w.y * qq.y + w.z * qq.z + w.w * qq.w;
    sk += w.x * kk.x + w.y * kk.y + w.z * kk.z + w.w * kk.w;
  }
  wq[idx] = sq;
  wk[idx] = sk;
}

// ---------------- qx/kx: qx[n,r] = X[n,:] . wq[r,:] (pure fp32) ----------------

__global__ __launch_bounds__(256) void k_qkx(const float* __restrict__ X,
                                             const float* __restrict__ wq,
                                             const float* __restrict__ wk,
                                             float* __restrict__ qx, float* __restrict__ kx) {
  int t = blockIdx.x * 256 + threadIdx.x;
  int n = t >> 4;
  if (n >= N_NODES) return;
  int idx = t & 15;
  int r = idx >> 1;
  int isk = idx & 1;
  const float4* xv = (const float4*)(X + (size_t)n * 128);
  const float4* wv = (const float4*)((isk ? wk : wq) + r * 128);
  float s = 0.f;
#pragma unroll 8
  for (int i = 0; i < 32; ++i) {
    float4 a = xv[i], b = wv[i];
    s += a.x * b.x + a.y * b.y + a.z * b.z + a.w * b.w;
  }
  (isk ? kx : qx)[n * R_REL + r] = s;
}

// ---------------- phase A: per-dst online-softmax, accumulate INPUT features per relation ----
// agg[d][r][f] (bf16) = sum_{e: dst=d, et=r} w_e * x[src_e][f].  One wave per node,
// lane holds float2 (feats 2l,2l+1) per relation; j-loop unrolled x4 for MLP.

__global__ __launch_bounds__(64) void k_agg_feat(
    const float* __restrict__ x, const float* __restrict__ qx, const float* __restrict__ kx,
    const int* __restrict__ rowptr, const int* __restrict__ ssrc, const int* __restrict__ setype,
    __bf16* __restrict__ agg)
{
  const int nd = blockIdx.x;
  const int lane = threadIdx.x;
  const int s = rowptr[nd];
  const int deg = rowptr[nd + 1] - s;

  float m = -INFINITY, sum = 0.f;
  float2 acc[R_REL];
#pragma unroll
  for (int r = 0; r < R_REL; ++r) acc[r] = make_float2(0.f, 0.f);
  const float2* x2 = (const float2*)x;

  for (int c = 0; c < deg; c += 64) {
    int idx = c + lane;
    bool valid = idx < deg;
    int sn = 0, et = 0;
    float a = -INFINITY;
    if (valid) {
      sn = ssrc[s + idx];
      et = setype[s + idx];
      a = qx[nd * R_REL + et] + kx[sn * R_REL + et];
      a = (a >= 0.f) ? a : 0.2f * a;   // leaky relu, slope 0.2
    }
    float cm = a;
#pragma unroll
    for (int off = 32; off > 0; off >>= 1) cm = fmaxf(cm, __shfl_xor(cm, off));
    float mnew = fmaxf(m, cm);
    float scale = (m == -INFINITY) ? 0.f : __expf(m - mnew);
    sum *= scale;
#pragma unroll
    for (int r = 0; r < R_REL; ++r) { acc[r].x *= scale; acc[r].y *= scale; }
    m = mnew;
    float e = valid ? __expf(a - m) : 0.f;
    float cs = e;
#pragma unroll
    for (int off = 32; off > 0; off >>= 1) cs += __shfl_xor(cs, off);
    sum += cs;
    int cnt = (deg - c < 64) ? (deg - c) : 64;

#define ACC_EDGE(W_, V_, E_)                                             \
    switch (E_) {                                                        \
      case 0: acc[0].x += W_ * V_.x; acc[0].y += W_ * V_.y; break;       \
      case 1: acc[1].x += W_ * V_.x; acc[1].y += W_ * V_.y; break;       \
      case 2: acc[2].x += W_ * V_.x; acc[2].y += W_ * V_.y; break;       \
      case 3: acc[3].x += W_ * V_.x; acc[3].y += W_ * V_.y; break;       \
      case 4: acc[4].x += W_ * V_.x; acc[4].y += W_ * V_.y; break;       \
      case 5: acc[5].x += W_ * V_.x; acc[5].y += W_ * V_.y; break;       \
      case 6: acc[6].x += W_ * V_.x; acc[6].y += W_ * V_.y; break;       \
      default: acc[7].x += W_ * V_.x; acc[7].y += W_ * V_.y; break;      \
    }

    int j = 0;
    for (; j + 4 <= cnt; j += 4) {
      float w0 = __shfl(e, j),     w1 = __shfl(e, j + 1);
      float w2 = __shfl(e, j + 2), w3 = __shfl(e, j + 3);
      int s0 = __shfl(sn, j),     s1 = __shfl(sn, j + 1);
      int s2 = __shfl(sn, j + 2), s3 = __shfl(sn, j + 3);
      int e0 = __shfl(et, j),     e1 = __shfl(et, j + 1);
      int e2 = __shfl(et, j + 2), e3 = __shfl(et, j + 3);
      float2 v0 = x2[(size_t)s0 * 64 + lane];
      float2 v1 = x2[(size_t)s1 * 64 + lane];
      float2 v2 = x2[(size_t)s2 * 64 + lane];
      float2 v3 = x2[(size_t)s3 * 64 + lane];
      ACC_EDGE(w0, v0, e0)
      ACC_EDGE(w1, v1, e1)
      ACC_EDGE(w2, v2, e2)
      ACC_EDGE(w3, v3, e3)
    }
    for (; j < cnt; ++j) {
      float w = __shfl(e, j);
      int sj = __shfl(sn, j);
      int ej = __shfl(et, j);
      float2 v = x2[(size_t)sj * 64 + lane];
      ACC_EDGE(w, v, ej)
    }
#undef ACC_EDGE
  }
  float inv = (deg > 0) ? 1.f / sum : 0.f;
  bf16x2* ag2 = (bf16x2*)agg;
#pragma unroll
  for (int r = 0; r < R_REL; ++r) {
    bf16x2 o;
    o[0] = (__bf16)(acc[r].x * inv);
    o[1] = (__bf16)(acc[r].y * inv);
    ag2[((size_t)nd * R_REL + r) * 64 + lane] = o;
  }
}

// ---------------- phase B: h[n,:] = relu( sum_k agg[n][k] * Wcat[k][:] + b ) ----------------
// M=128 outputs, K=1024 (r,f concat), N=node. block 512 = 8 waves x 16 nodes = 128 nodes.
// agg is bf16 -> B fragments load directly (no conversion); W split-bf16 -> 2 MFMAs/step.

__global__ __launch_bounds__(512, 4) void k_gemm_out(
    const __bf16* __restrict__ agg,
    const __bf16* __restrict__ Fhi, const __bf16* __restrict__ Flo,
    const float* __restrict__ bias, float* __restrict__ out)
{
  __shared__ bf16x8 sW[4096];            // [0,2048) hi, [2048,4096) lo — 64 KB
  const int tid  = threadIdx.x;
  const int wave = tid >> 6;
  const int lane = tid & 63;
  const int quad = lane >> 4;
  const int c    = lane & 15;

  const int node = blockIdx.x * 128 + wave * 16 + c;
  const int nclamp = (node < N_NODES) ? node : (N_NODES - 1);
  const bf16x8* Av = (const bf16x8*)(agg + (size_t)nclamp * 1024);

  f32x4 acc[8];
#pragma unroll
  for (int ot = 0; ot < 8; ++ot) acc[ot] = (f32x4){0.f, 0.f, 0.f, 0.f};

#pragma unroll 1
  for (int s = 0; s < 8; ++s) {          // K super-chunks of 128
    __syncthreads();
    {
      const float4* gh = (const float4*)(Fhi + (size_t)s * 16384);
      const float4* gl = (const float4*)(Flo + (size_t)s * 16384);
      float4* s4 = (float4*)sW;
#pragma unroll
      for (int i = 0; i < 4; ++i) {
        s4[tid + i * 512] = gh[tid + i * 512];
        s4[2048 + tid + i * 512] = gl[tid + i * 512];
      }
    }
    // B fragments (bf16 direct): agg[node][s*128 + kb*32 + quad*8 .. +8]
    bf16x8 B[4];
#pragma unroll
    for (int kb = 0; kb < 4; ++kb) B[kb] = Av[s * 16 + kb * 4 + quad];
    __syncthreads();
#pragma unroll
    for (int kb = 0; kb < 4; ++kb) {
#pragma unroll
      for (int ot = 0; ot < 8; ++ot) {
        bf16x8 whi = sW[(kb * 8 + ot) * 64 + lane];
        bf16x8 wlo = sW[2048 + (kb * 8 + ot) * 64 + lane];
        acc[ot] = __builtin_amdgcn_mfma_f32_16x16x32_bf16(whi, B[kb], acc[ot], 0, 0, 0);
        acc[ot] = __builtin_amdgcn_mfma_f32_16x16x32_bf16(wlo, B[kb], acc[ot], 0, 0, 0);
      }
    }
  }

  // D: col=node(c), row = o = ot*16 + quad*4 + reg.  Fuse bias + relu.
  if (node < N_NODES) {
    float* dp = out + ((size_t)node << 7) + quad * 4;
#pragma unroll
    for (int ot = 0; ot < 8; ++ot) {
      float4 bb = *(const float4*)(bias + ot * 16 + quad * 4);
      *(float4*)(dp + ot * 16) = make_float4(
          fmaxf(acc[ot][0] + bb.x, 0.f), fmaxf(acc[ot][1] + bb.y, 0.f),
          fmaxf(acc[ot][2] + bb.z, 0.f), fmaxf(acc[ot][3] + bb.w, 0.f));
    }
  }
}

// ---------------- final linear + log_softmax ----------------

__global__ __launch_bounds__(64) void k_final(
    const float* __restrict__ h, const float* __restrict__ lw, const float* __restrict__ lb,
    float* __restrict__ out)
{
  const int nd = blockIdx.x;
  const int c = threadIdx.x;
  const float* hrow = h + (size_t)nd * 128;
  float acc = lb[c];
#pragma unroll 8
  for (int f = 0; f < 128; ++f) acc += hrow[f] * lw[f * 64 + c];
  float mx = acc;
#pragma unroll
  for (int off = 32; off > 0; off >>= 1) mx = fmaxf(mx, __shfl_xor(mx, off));
  float e = __expf(acc - mx);
  float ssum = e;
#pragma unroll
  for (int off = 32; off > 0; off >>= 1) ssum += __shfl_xor(ssum, off);
  out[(size_t)nd * 64 + c] = acc - mx - __logf(ssum);
}

// ---------------- launch ----------------

extern "C" void kernel_launch(void* const* d_in, const int* in_sizes, int n_in,
                              void* d_out, int out_size, void* d_ws, size_t ws_size,
                              hipStream_t stream) {
  const float* x   = (const float*)d_in[0];
  const int* ei    = (const int*)d_in[1];
  const int* etype = (const int*)d_in[2];
  const float* W1 = (const float*)d_in[3];
  const float* q1 = (const float*)d_in[4];
  const float* k1 = (const float*)d_in[5];
  const float* b1 = (const float*)d_in[6];
  const float* W2 = (const float*)d_in[7];
  const float* q2 = (const float*)d_in[8];
  const float* k2 = (const float*)d_in[9];
  const float* b2 = (const float*)d_in[10];
  const float* W3 = (const float*)d_in[11];
  const float* q3 = (const float*)d_in[12];
  const float* k3 = (const float*)d_in[13];
  const float* b3 = (const float*)d_in[14];
  const float* lw = (const float*)d_in[15];
  const float* lb = (const float*)d_in[16];
  float* outp = (float*)d_out;

  char* p = (char*)d_ws;
  auto alloc = [&](size_t bytes) {
    char* r = p;
    p += (bytes + 255) & ~(size_t)255;
    return r;
  };
  __bf16* agg = (__bf16*)alloc((size_t)N_NODES * R_REL * H_DIM * 2);  // 102.4 MB
  float* qx   = (float*)alloc((size_t)N_NODES * R_REL * 4);
  float* kx   = (float*)alloc((size_t)N_NODES * R_REL * 4);
  float* hA   = (float*)alloc((size_t)N_NODES * H_DIM * 4);
  float* hB   = (float*)alloc((size_t)N_NODES * H_DIM * 4);
  int* rowptr = (int*)alloc((size_t)(N_NODES + 1) * 4);
  int* cursor = (int*)alloc((size_t)N_NODES * 4);
  int* hist   = (int*)alloc((size_t)N_NODES * 4);
  int* excl   = (int*)alloc((size_t)N_NODES * 4);
  int* bsum   = (int*)alloc((size_t)64 * 4);
  int* boff   = (int*)alloc((size_t)64 * 4);
  int* ssrc   = (int*)alloc((size_t)N_EDGES * 4);
  int* setype = (int*)alloc((size_t)N_EDGES * 4);
  __bf16* Fhi = (__bf16*)alloc((size_t)3 * 131072 * 2);   // 786 KB
  __bf16* Flo = (__bf16*)alloc((size_t)3 * 131072 * 2);
  float* wq   = (float*)alloc((size_t)3 * R_REL * 128 * 4);
  float* wk   = (float*)alloc((size_t)3 * R_REL * 128 * 4);

  const int* src = ei;            // edge_index[0]
  const int* dst = ei + N_EDGES;  // edge_index[1]

  const int nscan = (N_NODES + 1023) / 1024;

  // CSR build + W prep
  hipMemsetAsync(hist, 0, (size_t)N_NODES * 4, stream);
  k_hist<<<(N_EDGES + 255) / 256, 256, 0, stream>>>(dst, hist);
  k_prepwfrag<<<192, 256, 0, stream>>>(W1, W2, W3, Fhi, Flo);
  k_prepwq<<<(3 * R_REL * 128 + 255) / 256, 256, 0, stream>>>(W1, W2, W3, q1, k1, q2, k2, q3, k3, wq, wk);
  k_scan1<<<nscan, 1024, 0, stream>>>(hist, excl, bsum);
  k_scan2<<<1, 64, 0, stream>>>(bsum, boff);
  k_scan3<<<(N_NODES + 255) / 256, 256, 0, stream>>>(excl, boff, rowptr, cursor);
  k_scatter<<<(N_EDGES + 255) / 256, 256, 0, stream>>>(src, dst, etype, cursor, ssrc, setype);

  const int qgrid = (N_NODES * 16 + 255) / 256;
  const int ggrid = (N_NODES + 127) / 128;
  const size_t WFL = 131072;                     // per-layer fragment stride (bf16 elems)
  const size_t WQL = (size_t)R_REL * 128;

  // layer 1
  k_qkx<<<qgrid, 256, 0, stream>>>(x, wq, wk, qx, kx);
  k_agg_feat<<<N_NODES, 64, 0, stream>>>(x, qx, kx, rowptr, ssrc, setype, agg);
  k_gemm_out<<<ggrid, 512, 0, stream>>>(agg, Fhi, Flo, b1, hA);
  // layer 2
  k_qkx<<<qgrid, 256, 0, stream>>>(hA, wq + WQL, wk + WQL, qx, kx);
  k_agg_feat<<<N_NODES, 64, 0, stream>>>(hA, qx, kx, rowptr, ssrc, setype, agg);
  k_gemm_out<<<ggrid, 512, 0, stream>>>(agg, Fhi + WFL, Flo + WFL, b2, hB);
  // layer 3
  k_qkx<<<qgrid, 256, 0, stream>>>(hB, wq + 2 * WQL, wk + 2 * WQL, qx, kx);
  k_agg_feat<<<N_NODES, 64, 0, stream>>>(hB, qx, kx, rowptr, ssrc, setype, agg);
  k_gemm_out<<<ggrid, 512, 0, stream>>>(agg, Fhi + 2 * WFL, Flo + 2 * WFL, b3, hA);
  // final linear + log_softmax
  k_final<<<N_NODES, 64, 0, stream>>>(hA, lw, lb, outp);
}